// Round 13
// baseline (82.438 us; speedup 1.0000x reference)
//
#include <hip/hip_runtime.h>

// Stand-alone self-attention block, fully fused.
// x:(8,64,128,128) f32 -> out same shape. G=8, Cg=8, 3x3 window, pad 1.
//
// R13 = R12 (full-width 128x8 row-strips x 2-ch chunk, 4096 blocks,
// coalesced dwordx4 VMEM only, de-interleaved k/v LDS planes, wave-0
// halo rows, SGPR weights, streaming no-max exp2 softmax) WITHOUT the
// shuffle edge path (fault isolation for R12's correctness failure):
//  - window edge cols (x0-1, x0+4) = guarded scalar LDS reads
//    (x0==0 / x0==124 -> 0 = image zero-pad)
//  - center window row read from LDS like the others (no reg shortcut)

typedef float v4f __attribute__((ext_vector_type(4)));

#define HH 128
#define WW 128
#define HW (HH * WW)
#define LSTR 132       // plane row stride in floats (128 + 4 pad)
#define LOG2E 1.44269504088896f

__device__ __forceinline__ float sload(float v) {
    // force block-uniform value into an SGPR
    return __uint_as_float(__builtin_amdgcn_readfirstlane(__float_as_uint(v)));
}

__global__ __launch_bounds__(256, 5) void sab_fused(
    const float* __restrict__ x,
    const float* __restrict__ Wq,
    const float* __restrict__ Wk,
    const float* __restrict__ Wv,
    const float* __restrict__ h_emb,
    const float* __restrict__ w_emb,
    float* __restrict__ out)
{
    __shared__ float kpl[2][10][LSTR];   // k planes: lds row r = image row h0+r-1
    __shared__ float vpl[2][10][LSTR];   // v planes             (21.1 KB total)

    const int bid0 = blockIdx.x;
    const int work = (bid0 & 7) * 512 + (bid0 >> 3);   // bijective XCD swizzle
    const int c0   = (work & 3) << 1;          // channel chunk {0,2,4,6}
    const int tile = (work >> 2) & 15;         // 16 row-strips of 8 rows
    const int bg   = work >> 6;                // b*8 + g
    const int g    = bg & 7;
    const int h0   = tile << 3;
    const int tid  = threadIdx.x;
    const int ty   = tid >> 5;                 // 0..7
    const int x0   = (tid & 31) << 2;          // 0,4,..,124

    // ---- weights + emb -> SGPRs (readfirstlane-forced) ----
    float wk[2][8], wv[2][8], wq[2][8], eb[2][9];
    #pragma unroll
    for (int cc = 0; cc < 2; cc++) {
        const int c = c0 + cc;
        #pragma unroll
        for (int i = 0; i < 8; i++) {
            wk[cc][i] = sload(Wk[g * 64 + c * 8 + i]);
            wv[cc][i] = sload(Wv[g * 64 + c * 8 + i]);
            wq[cc][i] = sload(Wq[g * 64 + c * 8 + i]);
        }
        #pragma unroll
        for (int p = 0; p < 9; p++) {
            // channels 0-3: h_emb (ki = p/3); 4-7: w_emb (kj = p%3)
            eb[cc][p] = sload((c < 4) ? h_emb[(g * 4 + c) * 3 + p / 3]
                                      : w_emb[(g * 4 + c - 4) * 3 + p % 3]);
        }
    }

    const float* xb = x + (size_t)bg * 8 * HW;
    const int ibase = (h0 + ty) * WW + x0;

    // ---- interior x: 4 px, 8 channels (all dwordx4, fully coalesced) ----
    v4f xi[8];
    #pragma unroll
    for (int i = 0; i < 8; i++)
        xi[i] = *reinterpret_cast<const v4f*>(xb + i * HW + ibase);

    // ---- conv (packed): k,v -> LDS planes, q -> regs ----
    v4f kk0 = 0.f, vv0 = 0.f, qq0 = 0.f, kk1 = 0.f, vv1 = 0.f, qq1 = 0.f;
    #pragma unroll
    for (int i = 0; i < 8; i++) {
        const v4f xv = xi[i];
        kk0 += wk[0][i] * xv;  vv0 += wv[0][i] * xv;  qq0 += wq[0][i] * xv;
        kk1 += wk[1][i] * xv;  vv1 += wv[1][i] * xv;  qq1 += wq[1][i] * xv;
    }
    *reinterpret_cast<v4f*>(&kpl[0][ty + 1][x0]) = kk0;
    *reinterpret_cast<v4f*>(&vpl[0][ty + 1][x0]) = vv0;
    *reinterpret_cast<v4f*>(&kpl[1][ty + 1][x0]) = kk1;
    *reinterpret_cast<v4f*>(&vpl[1][ty + 1][x0]) = vv1;
    const v4f q0 = qq0 * LOG2E;
    const v4f q1 = qq1 * LOG2E;

    // ---- halo rows (-1 and +8): threads 0..63, same coalesced packed code ----
    if (tid < 64) {
        const int hr  = tid >> 5;              // 0: above, 1: below
        const int hx0 = (tid & 31) << 2;
        const int gh  = h0 - 1 + hr * 9;       // image row
        const int lr  = hr * 9;                // LDS row 0 or 9
        v4f hk0 = 0.f, hv0 = 0.f, hk1 = 0.f, hv1 = 0.f;
        if (gh >= 0 && gh < HH) {
            const int base = gh * WW + hx0;
            #pragma unroll
            for (int i = 0; i < 8; i++) {
                const v4f xv = *reinterpret_cast<const v4f*>(xb + i * HW + base);
                hk0 += wk[0][i] * xv;  hv0 += wv[0][i] * xv;
                hk1 += wk[1][i] * xv;  hv1 += wv[1][i] * xv;
            }
        }
        *reinterpret_cast<v4f*>(&kpl[0][lr][hx0]) = hk0;
        *reinterpret_cast<v4f*>(&vpl[0][lr][hx0]) = hv0;
        *reinterpret_cast<v4f*>(&kpl[1][lr][hx0]) = hk1;
        *reinterpret_cast<v4f*>(&vpl[1][lr][hx0]) = hv1;
    }
    __syncthreads();

    // ---- attention: 3 window rows from LDS; edges = guarded scalar reads ----
    float s[2][4] = {{0.f,0.f,0.f,0.f},{0.f,0.f,0.f,0.f}};
    float o[2][4] = {{0.f,0.f,0.f,0.f},{0.f,0.f,0.f,0.f}};

    #pragma unroll
    for (int cc = 0; cc < 2; cc++) {
        #pragma unroll
        for (int dh = 0; dh < 3; dh++) {
            const int lr = ty + dh;            // image row h0+ty-1+dh
            const v4f Bk = *reinterpret_cast<const v4f*>(&kpl[cc][lr][x0]);
            const v4f Bv = *reinterpret_cast<const v4f*>(&vpl[cc][lr][x0]);
            const float kL = x0        ? kpl[cc][lr][x0 - 1] : 0.f;
            const float vL = x0        ? vpl[cc][lr][x0 - 1] : 0.f;
            const float kR = (x0 < 124) ? kpl[cc][lr][x0 + 4] : 0.f;
            const float vR = (x0 < 124) ? vpl[cc][lr][x0 + 4] : 0.f;
            const float kw[6] = {kL, Bk.x, Bk.y, Bk.z, Bk.w, kR};
            const float vw[6] = {vL, Bv.x, Bv.y, Bv.z, Bv.w, vR};
            #pragma unroll
            for (int px = 0; px < 4; px++) {
                const float ql = (cc ? q1 : q0)[px];
                #pragma unroll
                for (int dw = 0; dw < 3; dw++) {
                    const float e = __builtin_amdgcn_exp2f(
                        ql * (kw[px + dw] + eb[cc][dh * 3 + dw]));
                    s[cc][px] += e;
                    o[cc][px] = fmaf(e, vw[px + dw], o[cc][px]);
                }
            }
        }
    }

    // ---- normalize + store (dwordx4 per channel, coalesced) ----
    v4f r0, r1;
    #pragma unroll
    for (int px = 0; px < 4; px++) {
        r0[px] = o[0][px] * __builtin_amdgcn_rcpf(s[0][px]);
        r1[px] = o[1][px] * __builtin_amdgcn_rcpf(s[1][px]);
    }
    *reinterpret_cast<v4f*>(out + (size_t)(bg * 8 + c0 + 0) * HW + ibase) = r0;
    *reinterpret_cast<v4f*>(out + (size_t)(bg * 8 + c0 + 1) * HW + ibase) = r1;
}

extern "C" void kernel_launch(void* const* d_in, const int* in_sizes, int n_in,
                              void* d_out, int out_size, void* d_ws, size_t ws_size,
                              hipStream_t stream) {
    const float* x    = (const float*)d_in[0];
    const float* Wq   = (const float*)d_in[1];
    const float* Wk   = (const float*)d_in[2];
    const float* Wv   = (const float*)d_in[3];
    const float* h_e  = (const float*)d_in[4];
    const float* w_e  = (const float*)d_in[5];
    float* out = (float*)d_out;

    dim3 grid(8 * 8 * 16 * 4);   // (b,g) x 16 row-strips x 4 channel-chunks
    dim3 block(256);
    sab_fused<<<grid, block, 0, stream>>>(x, Wq, Wk, Wv, h_e, w_e, out);
}

// Round 14
// 32.849 us; speedup vs baseline: 2.5096x; 2.5096x over previous
//
#include <hip/hip_runtime.h>

// Stand-alone self-attention block, fully fused.
// x:(8,64,128,128) f32 -> out same shape. G=8, Cg=8, 3x3 window, pad 1.
//
// R14 = R13 (full-width 128x8 row-strips x 2-ch chunk, 4096 blocks,
// coalesced dwordx4 VMEM only, de-interleaved k/v LDS planes, wave-0
// halo rows, SGPR weights, guarded-scalar window edges, streaming
// no-max exp2 softmax) with ONE change:
//  - plain __launch_bounds__(256): NO min-waves arg. (256,5) made the
//    allocator collapse to 48 VGPR + 204 MB scratch traffic on this
//    code shape (R13: 82 us). Forcing occupancy is retired for good
//    (R6, R9, R13 all collapsed; R7 clean-but-slower).

typedef float v4f __attribute__((ext_vector_type(4)));

#define HH 128
#define WW 128
#define HW (HH * WW)
#define LSTR 132       // plane row stride in floats (128 + 4 pad)
#define LOG2E 1.44269504088896f

__device__ __forceinline__ float sload(float v) {
    // force block-uniform value into an SGPR
    return __uint_as_float(__builtin_amdgcn_readfirstlane(__float_as_uint(v)));
}

__global__ __launch_bounds__(256) void sab_fused(
    const float* __restrict__ x,
    const float* __restrict__ Wq,
    const float* __restrict__ Wk,
    const float* __restrict__ Wv,
    const float* __restrict__ h_emb,
    const float* __restrict__ w_emb,
    float* __restrict__ out)
{
    __shared__ float kpl[2][10][LSTR];   // k planes: lds row r = image row h0+r-1
    __shared__ float vpl[2][10][LSTR];   // v planes             (21.1 KB total)

    const int bid0 = blockIdx.x;
    const int work = (bid0 & 7) * 512 + (bid0 >> 3);   // bijective XCD swizzle
    const int c0   = (work & 3) << 1;          // channel chunk {0,2,4,6}
    const int tile = (work >> 2) & 15;         // 16 row-strips of 8 rows
    const int bg   = work >> 6;                // b*8 + g
    const int g    = bg & 7;
    const int h0   = tile << 3;
    const int tid  = threadIdx.x;
    const int ty   = tid >> 5;                 // 0..7
    const int x0   = (tid & 31) << 2;          // 0,4,..,124

    // ---- weights + emb -> SGPRs (readfirstlane-forced) ----
    float wk[2][8], wv[2][8], wq[2][8], eb[2][9];
    #pragma unroll
    for (int cc = 0; cc < 2; cc++) {
        const int c = c0 + cc;
        #pragma unroll
        for (int i = 0; i < 8; i++) {
            wk[cc][i] = sload(Wk[g * 64 + c * 8 + i]);
            wv[cc][i] = sload(Wv[g * 64 + c * 8 + i]);
            wq[cc][i] = sload(Wq[g * 64 + c * 8 + i]);
        }
        #pragma unroll
        for (int p = 0; p < 9; p++) {
            // channels 0-3: h_emb (ki = p/3); 4-7: w_emb (kj = p%3)
            eb[cc][p] = sload((c < 4) ? h_emb[(g * 4 + c) * 3 + p / 3]
                                      : w_emb[(g * 4 + c - 4) * 3 + p % 3]);
        }
    }

    const float* xb = x + (size_t)bg * 8 * HW;
    const int ibase = (h0 + ty) * WW + x0;

    // ---- interior x: 4 px, 8 channels (all dwordx4, fully coalesced) ----
    v4f xi[8];
    #pragma unroll
    for (int i = 0; i < 8; i++)
        xi[i] = *reinterpret_cast<const v4f*>(xb + i * HW + ibase);

    // ---- conv (packed): k,v -> LDS planes, q -> regs ----
    v4f kk0 = 0.f, vv0 = 0.f, qq0 = 0.f, kk1 = 0.f, vv1 = 0.f, qq1 = 0.f;
    #pragma unroll
    for (int i = 0; i < 8; i++) {
        const v4f xv = xi[i];
        kk0 += wk[0][i] * xv;  vv0 += wv[0][i] * xv;  qq0 += wq[0][i] * xv;
        kk1 += wk[1][i] * xv;  vv1 += wv[1][i] * xv;  qq1 += wq[1][i] * xv;
    }
    *reinterpret_cast<v4f*>(&kpl[0][ty + 1][x0]) = kk0;
    *reinterpret_cast<v4f*>(&vpl[0][ty + 1][x0]) = vv0;
    *reinterpret_cast<v4f*>(&kpl[1][ty + 1][x0]) = kk1;
    *reinterpret_cast<v4f*>(&vpl[1][ty + 1][x0]) = vv1;
    const v4f q0 = qq0 * LOG2E;
    const v4f q1 = qq1 * LOG2E;

    // ---- halo rows (-1 and +8): threads 0..63, same coalesced packed code ----
    if (tid < 64) {
        const int hr  = tid >> 5;              // 0: above, 1: below
        const int hx0 = (tid & 31) << 2;
        const int gh  = h0 - 1 + hr * 9;       // image row
        const int lr  = hr * 9;                // LDS row 0 or 9
        v4f hk0 = 0.f, hv0 = 0.f, hk1 = 0.f, hv1 = 0.f;
        if (gh >= 0 && gh < HH) {
            const int base = gh * WW + hx0;
            #pragma unroll
            for (int i = 0; i < 8; i++) {
                const v4f xv = *reinterpret_cast<const v4f*>(xb + i * HW + base);
                hk0 += wk[0][i] * xv;  hv0 += wv[0][i] * xv;
                hk1 += wk[1][i] * xv;  hv1 += wv[1][i] * xv;
            }
        }
        *reinterpret_cast<v4f*>(&kpl[0][lr][hx0]) = hk0;
        *reinterpret_cast<v4f*>(&vpl[0][lr][hx0]) = hv0;
        *reinterpret_cast<v4f*>(&kpl[1][lr][hx0]) = hk1;
        *reinterpret_cast<v4f*>(&vpl[1][lr][hx0]) = hv1;
    }
    __syncthreads();

    // ---- attention: 3 window rows from LDS; edges = guarded scalar reads ----
    float s[2][4] = {{0.f,0.f,0.f,0.f},{0.f,0.f,0.f,0.f}};
    float o[2][4] = {{0.f,0.f,0.f,0.f},{0.f,0.f,0.f,0.f}};

    #pragma unroll
    for (int cc = 0; cc < 2; cc++) {
        #pragma unroll
        for (int dh = 0; dh < 3; dh++) {
            const int lr = ty + dh;            // image row h0+ty-1+dh
            const v4f Bk = *reinterpret_cast<const v4f*>(&kpl[cc][lr][x0]);
            const v4f Bv = *reinterpret_cast<const v4f*>(&vpl[cc][lr][x0]);
            const float kL = x0        ? kpl[cc][lr][x0 - 1] : 0.f;
            const float vL = x0        ? vpl[cc][lr][x0 - 1] : 0.f;
            const float kR = (x0 < 124) ? kpl[cc][lr][x0 + 4] : 0.f;
            const float vR = (x0 < 124) ? vpl[cc][lr][x0 + 4] : 0.f;
            const float kw[6] = {kL, Bk.x, Bk.y, Bk.z, Bk.w, kR};
            const float vw[6] = {vL, Bv.x, Bv.y, Bv.z, Bv.w, vR};
            #pragma unroll
            for (int px = 0; px < 4; px++) {
                const float ql = (cc ? q1 : q0)[px];
                #pragma unroll
                for (int dw = 0; dw < 3; dw++) {
                    const float e = __builtin_amdgcn_exp2f(
                        ql * (kw[px + dw] + eb[cc][dh * 3 + dw]));
                    s[cc][px] += e;
                    o[cc][px] = fmaf(e, vw[px + dw], o[cc][px]);
                }
            }
        }
    }

    // ---- normalize + store (dwordx4 per channel, coalesced) ----
    v4f r0, r1;
    #pragma unroll
    for (int px = 0; px < 4; px++) {
        r0[px] = o[0][px] * __builtin_amdgcn_rcpf(s[0][px]);
        r1[px] = o[1][px] * __builtin_amdgcn_rcpf(s[1][px]);
    }
    *reinterpret_cast<v4f*>(out + (size_t)(bg * 8 + c0 + 0) * HW + ibase) = r0;
    *reinterpret_cast<v4f*>(out + (size_t)(bg * 8 + c0 + 1) * HW + ibase) = r1;
}

extern "C" void kernel_launch(void* const* d_in, const int* in_sizes, int n_in,
                              void* d_out, int out_size, void* d_ws, size_t ws_size,
                              hipStream_t stream) {
    const float* x    = (const float*)d_in[0];
    const float* Wq   = (const float*)d_in[1];
    const float* Wk   = (const float*)d_in[2];
    const float* Wv   = (const float*)d_in[3];
    const float* h_e  = (const float*)d_in[4];
    const float* w_e  = (const float*)d_in[5];
    float* out = (float*)d_out;

    dim3 grid(8 * 8 * 16 * 4);   // (b,g) x 16 row-strips x 4 channel-chunks
    dim3 block(256);
    sab_fused<<<grid, block, 0, stream>>>(x, Wq, Wk, Wv, h_e, w_e, out);
}

// Round 15
// 30.776 us; speedup vs baseline: 2.6786x; 1.0673x over previous
//
#include <hip/hip_runtime.h>

// Stand-alone self-attention block, fully fused.
// x:(8,64,128,128) f32 -> out same shape. G=8, Cg=8, 3x3 window, pad 1.
//
// R15 = R11 (2-ch chunk, 4 px/thread, 4096 blocks, SGPR weights,
// interleaved float2 kv LDS, aligned b128 window reads, streaming
// no-max exp2 softmax, plain launch_bounds) with a 64x16 tile:
//  - column-halo scalar loads 66 -> 32 per block; row halos (132 px)
//    become dwordx4 loads like the interior. Only 36 scalar loads left.
//    Attacks the 57.4 vs 33.5 MB FETCH over-fetch (scattered 64B lines).
//  - LDS stride 70 float2: wave = 4 rows x 16 cols; b128 read start-bank
//    (12r + 2x0)%32 -> each 16B group serves exactly 2 lanes = 2-way = free.

typedef float v2f __attribute__((ext_vector_type(2)));
typedef float v4f __attribute__((ext_vector_type(4)));

#define HH 128
#define WW 128
#define HW (HH * WW)
#define PTS 70         // LDS row stride in float2 (66 + 4 pad; even -> b128 ok)
#define LOG2E 1.44269504088896f

__device__ __forceinline__ float sload(float v) {
    // force block-uniform value into an SGPR
    return __uint_as_float(__builtin_amdgcn_readfirstlane(__float_as_uint(v)));
}

__global__ __launch_bounds__(256) void sab_fused(
    const float* __restrict__ x,
    const float* __restrict__ Wq,
    const float* __restrict__ Wk,
    const float* __restrict__ Wv,
    const float* __restrict__ h_emb,
    const float* __restrict__ w_emb,
    float* __restrict__ out)
{
    __shared__ v2f kv[2][18][PTS];      // [cc][row][col] {k,v}  (19.7 KB)

    const int bid0 = blockIdx.x;
    const int work = (bid0 & 7) * 512 + (bid0 >> 3);   // bijective XCD swizzle
    const int c0   = (work & 3) << 1;          // channel chunk {0,2,4,6}
    const int tile = (work >> 2) & 15;         // 2 cols x 8 rows of 64x16 tiles
    const int bg   = work >> 6;                // b*8 + g
    const int g    = bg & 7;
    const int h0   = (tile >> 1) << 4;
    const int w0   = (tile & 1) << 6;
    const int tid  = threadIdx.x;
    const int ty   = tid >> 4;                 // 0..15
    const int x0   = (tid & 15) << 2;          // 0,4,..,60

    // ---- weights + emb -> SGPRs (readfirstlane-forced) ----
    float wk[2][8], wv[2][8], wq[2][8], eb[2][9];
    #pragma unroll
    for (int cc = 0; cc < 2; cc++) {
        const int c = c0 + cc;
        #pragma unroll
        for (int i = 0; i < 8; i++) {
            wk[cc][i] = sload(Wk[g * 64 + c * 8 + i]);
            wv[cc][i] = sload(Wv[g * 64 + c * 8 + i]);
            wq[cc][i] = sload(Wq[g * 64 + c * 8 + i]);
        }
        #pragma unroll
        for (int p = 0; p < 9; p++) {
            // channels 0-3: h_emb (ki = p/3); 4-7: w_emb (kj = p%3)
            eb[cc][p] = sload((c < 4) ? h_emb[(g * 4 + c) * 3 + p / 3]
                                      : w_emb[(g * 4 + c - 4) * 3 + p % 3]);
        }
    }

    const float* xb = x + (size_t)bg * 8 * HW;
    const int ibase = (h0 + ty) * WW + (w0 + x0);

    // ---- interior x: 4 px, 8 channels (dwordx4) ----
    v4f xi[8];
    #pragma unroll
    for (int i = 0; i < 8; i++)
        xi[i] = *reinterpret_cast<const v4f*>(xb + i * HW + ibase);

    // ---- conv (packed): k,v -> LDS, q -> regs ----
    v4f kk0 = 0.f, vv0 = 0.f, qq0 = 0.f, kk1 = 0.f, vv1 = 0.f, qq1 = 0.f;
    #pragma unroll
    for (int i = 0; i < 8; i++) {
        const v4f xv = xi[i];
        kk0 += wk[0][i] * xv;  vv0 += wv[0][i] * xv;  qq0 += wq[0][i] * xv;
        kk1 += wk[1][i] * xv;  vv1 += wv[1][i] * xv;  qq1 += wq[1][i] * xv;
    }
    #pragma unroll
    for (int px = 0; px < 4; px++) {
        kv[0][ty + 1][x0 + 1 + px] = (v2f){kk0[px], vv0[px]};
        kv[1][ty + 1][x0 + 1 + px] = (v2f){kk1[px], vv1[px]};
    }
    const v4f q0 = qq0 * LOG2E;
    const v4f q1 = qq1 * LOG2E;

    // ---- halo ----
    if (tid < 32) {
        // top/bottom rows, aligned 64 px each: dwordx4 path
        const int hr  = tid >> 4;              // 0: top, 1: bottom
        const int t   = tid & 15;
        const int gh  = hr ? (h0 + 16) : (h0 - 1);
        const int lr  = hr ? 17 : 0;
        const int gw  = w0 + (t << 2);
        v4f hk0 = 0.f, hv0 = 0.f, hk1 = 0.f, hv1 = 0.f;
        if (gh >= 0 && gh < HH) {
            const int base = gh * WW + gw;
            #pragma unroll
            for (int i = 0; i < 8; i++) {
                const v4f xv = *reinterpret_cast<const v4f*>(xb + i * HW + base);
                hk0 += wk[0][i] * xv;  hv0 += wv[0][i] * xv;
                hk1 += wk[1][i] * xv;  hv1 += wv[1][i] * xv;
            }
        }
        #pragma unroll
        for (int px = 0; px < 4; px++) {
            kv[0][lr][1 + (t << 2) + px] = (v2f){hk0[px], hv0[px]};
            kv[1][lr][1 + (t << 2) + px] = (v2f){hk1[px], hv1[px]};
        }
    } else if (tid < 68) {
        // side columns (32 px) + 4 corners: scalar path
        int hpy, hpx, gh, gw;
        if (tid < 48)      { hpy = 1 + (tid - 32); hpx = 0;  gh = h0 + (tid - 32); gw = w0 - 1; }
        else if (tid < 64) { hpy = 1 + (tid - 48); hpx = 65; gh = h0 + (tid - 48); gw = w0 + 64; }
        else {
            const int t = tid - 64;
            const int cy = t >> 1, cx = t & 1;
            hpy = cy ? 17 : 0;
            hpx = cx ? 65 : 0;
            gh  = cy ? (h0 + 16) : (h0 - 1);
            gw  = cx ? (w0 + 64) : (w0 - 1);
        }
        const bool ok = (gh >= 0) & (gh < HH) & (gw >= 0) & (gw < WW);
        const int base = gh * WW + gw;
        float hk0 = 0.f, hv0 = 0.f, hk1 = 0.f, hv1 = 0.f;
        #pragma unroll
        for (int i = 0; i < 8; i++) {
            const float xv = ok ? xb[i * HW + base] : 0.0f;
            hk0 = fmaf(wk[0][i], xv, hk0);
            hv0 = fmaf(wv[0][i], xv, hv0);
            hk1 = fmaf(wk[1][i], xv, hk1);
            hv1 = fmaf(wv[1][i], xv, hv1);
        }
        kv[0][hpy][hpx] = (v2f){hk0, hv0};
        kv[1][hpy][hpx] = (v2f){hk1, hv1};
    }
    __syncthreads();

    // ---- attention: scalar streaming softmax, 3 aligned b128 per row ----
    float s[2][4] = {{0.f,0.f,0.f,0.f},{0.f,0.f,0.f,0.f}};
    float o[2][4] = {{0.f,0.f,0.f,0.f},{0.f,0.f,0.f,0.f}};
    #pragma unroll
    for (int dh = 0; dh < 3; dh++) {
        #pragma unroll
        for (int cc = 0; cc < 2; cc++) {
            const v2f* row = &kv[cc][ty + dh][x0];
            const v4f a  = *reinterpret_cast<const v4f*>(row);      // k0 v0 k1 v1
            const v4f bq = *reinterpret_cast<const v4f*>(row + 2);  // k2 v2 k3 v3
            const v4f cq = *reinterpret_cast<const v4f*>(row + 4);  // k4 v4 k5 v5
            const float kw[6] = {a.x, a.z, bq.x, bq.z, cq.x, cq.z};
            const float vw[6] = {a.y, a.w, bq.y, bq.w, cq.y, cq.w};
            #pragma unroll
            for (int px = 0; px < 4; px++) {
                const float ql = (cc ? q1 : q0)[px];
                #pragma unroll
                for (int dw = 0; dw < 3; dw++) {
                    const float e = __builtin_amdgcn_exp2f(
                        ql * (kw[px + dw] + eb[cc][dh * 3 + dw]));
                    s[cc][px] += e;
                    o[cc][px] = fmaf(e, vw[px + dw], o[cc][px]);
                }
            }
        }
    }

    // ---- normalize + store (dwordx4 per channel) ----
    v4f r0, r1;
    #pragma unroll
    for (int px = 0; px < 4; px++) {
        r0[px] = o[0][px] * __builtin_amdgcn_rcpf(s[0][px]);
        r1[px] = o[1][px] * __builtin_amdgcn_rcpf(s[1][px]);
    }
    *reinterpret_cast<v4f*>(out + (size_t)(bg * 8 + c0 + 0) * HW + ibase) = r0;
    *reinterpret_cast<v4f*>(out + (size_t)(bg * 8 + c0 + 1) * HW + ibase) = r1;
}

extern "C" void kernel_launch(void* const* d_in, const int* in_sizes, int n_in,
                              void* d_out, int out_size, void* d_ws, size_t ws_size,
                              hipStream_t stream) {
    const float* x    = (const float*)d_in[0];
    const float* Wq   = (const float*)d_in[1];
    const float* Wk   = (const float*)d_in[2];
    const float* Wv   = (const float*)d_in[3];
    const float* h_e  = (const float*)d_in[4];
    const float* w_e  = (const float*)d_in[5];
    float* out = (float*)d_out;

    dim3 grid(8 * 8 * 16 * 4);   // (b,g) x 16 tiles x 4 channel-chunks
    dim3 block(256);
    sab_fused<<<grid, block, 0, stream>>>(x, Wq, Wk, Wv, h_e, w_e, out);
}